// Round 4
// baseline (1622.302 us; speedup 1.0000x reference)
//
#include <hip/hip_runtime.h>
#include <math.h>

#define DEV static __device__ __forceinline__

// ---- problem constants ----
#define B_   2
#define N_   4
#define T_   512
#define D_   1024
#define DK_  64
#define H_   8
#define E_   6
#define DV_  64
#define DKP_ 128
#define HE_  48
#define R_   16
#define DA_  103
#define CC_  512
#define DPG_ 316
#define ND_  4096
#define U_   1024      // B*T tokens

typedef unsigned short u16;
typedef __attribute__((ext_vector_type(8))) unsigned short us8;
typedef __attribute__((ext_vector_type(8))) short bhalf8;
typedef __attribute__((ext_vector_type(4))) float f32x4;

struct P {
  // inputs
  const float *stream, *freqs, *pope_delta;
  const float *W_q, *W_k, *W_v, *q_rw, *kv_rw;
  const float *lA_q, *lB_q, *lA_k, *lB_k, *lA_v, *lB_v;
  const float *a_up, *a_dn, *b_up, *b_dn;
  const float *mhc_norm, *phi_pre, *phi_post, *phi_res;
  const float *b_pre, *b_post, *b_res, *al_pre, *al_post, *al_res;
  const float *bn_w, *W_pre, *W_o, *W_pg1, *W_pg2;
  // workspace
  int *qsel, *kvsel, *qcnt, *kvcnt, *qlist, *kvlist;
  float *scale, *mhc_partial;
  float *Hpre_q, *Hpre_kv, *Hres, *Hpost;
  float *kv_lin, *aup, *bup, *pre_logit, *post_logit;
  float *la_k, *la_v, *la_q, *q_lin;
  float *a_buf, *b_buf, *q_buf, *k_buf, *v_buf;
  float *attn, *y;
  float *out;
  u16 *xb;                       // bf16 rms-scaled x, (U, ND)
  u16 *he_kvB, *he_qB, *pgB;
  u16 *Bt0, *Bt1, *Bt2, *Bt3, *Bt4;
};

DEV float sigm(float x){ return 1.f/(1.f+expf(-x)); }
DEV float softplus_(float x){ return x>0.f ? x+log1pf(expf(-x)) : log1pf(expf(x)); }
DEV float silu_(float x){ return x*sigm(x); }
DEV u16 f2b(float x){ unsigned u = __float_as_uint(x); u += 0x7FFFu + ((u>>16)&1u); return (u16)(u>>16); }

DEV float block_reduce_sum(float v, float* sm){
  __syncthreads();
  int lane = threadIdx.x & 63, w = threadIdx.x >> 6;
  for (int off=32; off; off>>=1) v += __shfl_down(v, off, 64);
  if (lane==0) sm[w] = v;
  __syncthreads();
  if (threadIdx.x == 0){
    float s = 0; int nw = blockDim.x >> 6;
    for (int i=0;i<nw;i++) s += sm[i];
    sm[0] = s;
  }
  __syncthreads();
  return sm[0];
}

// ============================ prep kernels (bf16 B panels) ============================

__global__ void k_prep0(P p){
  int j = blockIdx.x; int k = j/24, r = j%24;
  const float* src;
  if (r < 4)      src = p.phi_pre  + (size_t)(k*4+r)*ND_;
  else if (r < 8) src = p.phi_post + (size_t)(k*4+(r-4))*ND_;
  else            src = p.phi_res  + (size_t)(k*16+(r-8))*ND_;
  const float* mn = p.mhc_norm + (size_t)k*ND_;
  u16* d = p.Bt0 + (size_t)j*ND_;
  for (int i = threadIdx.x; i < ND_; i += 256) d[i] = f2b(src[i]*mn[i]);
}

__global__ void k_prep1d(P p){
  int r = blockIdx.x, g = blockIdx.y, h = g/E_;
  u16* drow = p.Bt1 + (size_t)g*1216*1024 + (size_t)(r<128 ? r : 1194 + (r-128))*1024;
  const float* srow = (r<64) ? (p.W_k + ((size_t)h*64 + r)*1024)
                   : (r<128) ? (p.W_v + ((size_t)h*64 + (r-64))*1024) : nullptr;
  for (int k2 = threadIdx.x; k2 < 1024; k2 += 256)
    drow[k2] = (r<128) ? f2b(srow[k2]) : (u16)0;
}

__global__ void k_prep2d(P p){
  int r = blockIdx.x, g = blockIdx.y, h = g/E_;
  u16* drow = p.Bt2 + (size_t)g*128*1024 + (size_t)r*1024;
  const float* srow = p.W_q + ((size_t)h*64 + r)*1024;
  for (int k2 = threadIdx.x; k2 < 1024; k2 += 256) drow[k2] = f2b(srow[k2]);
}

__global__ void k_prep4(P p){
  int r = blockIdx.x;
  u16* drow = p.Bt4 + (size_t)r*512;
  const float* srow = p.W_o + (size_t)r*512;
  for (int c = threadIdx.x; c < 512; c += 256) drow[c] = f2b(srow[c]);
}

__global__ void k_prept(const float* src, long sstride, int ld, int ncols,
                        u16* dst, long dstride, int dld, int K, int Ksrc){
  __shared__ float t[32][33];
  const float* S = src + (size_t)blockIdx.z*sstride;
  u16* Dp = dst + (size_t)blockIdx.z*dstride;
  int k0 = blockIdx.x*32, c0 = blockIdx.y*32;
  int tx = threadIdx.x & 31, ty = threadIdx.x >> 5;
  #pragma unroll
  for (int i=0;i<32;i+=8){
    int k = k0+ty+i, c = c0+tx;
    t[ty+i][tx] = (k < Ksrc && c < ncols) ? S[(size_t)k*ld + c] : 0.f;
  }
  __syncthreads();
  #pragma unroll
  for (int i=0;i<32;i+=8){
    int c = c0+ty+i, k = k0+tx;
    if (c < ncols && k < K) Dp[(size_t)c*dld + k] = f2b(t[tx][ty+i]);
  }
}

// ============================ routing + rms-scale + bf16 x ============================

__global__ void k_route(P p){
  int u = blockIdx.x, b = u>>9, t = u&511;
  __shared__ float ri[D_];
  __shared__ float lg[2][HE_];
  __shared__ float sm[8];
  int tid = threadIdx.x;
  float sv[4][4]; float ss = 0.f;
  #pragma unroll
  for (int j=0;j<4;j++){
    int d = tid + j*256;
    float acc = 0;
    #pragma unroll
    for (int n = 0; n < 4; n++){
      float v = p.stream[(((size_t)(b*N_+n)*T_)+t)*D_ + d];
      sv[j][n] = v; acc += v; ss += v*v;
    }
    ri[d] = acc * 0.25f;
  }
  ss = block_reduce_sum(ss, sm);
  float sc = rsqrtf(ss/(float)ND_ + 1e-8f);
  if (tid==0) p.scale[u] = sc;
  #pragma unroll
  for (int j=0;j<4;j++){
    int d = tid + j*256;
    #pragma unroll
    for (int n=0;n<4;n++)
      p.xb[(size_t)u*ND_ + n*D_ + d] = f2b(sv[j][n]*sc);
  }
  int lane = tid & 63, wv = tid >> 6;
  for (int j = wv; j < 2*HE_; j += 4){
    const float* w = (j < HE_ ? p.q_rw : p.kv_rw) + (size_t)(j % HE_)*D_;
    float acc = 0;
    for (int d = lane; d < D_; d += 64) acc += ri[d]*w[d];
    for (int off=32; off; off>>=1) acc += __shfl_down(acc, off, 64);
    if (lane==0) lg[j/HE_][j%HE_] = acc;
  }
  __syncthreads();
  if (tid < 16){
    int h = tid & 7, which = tid >> 3;
    const float* L = lg[which] + h*E_;
    float best = fminf(fmaxf(L[0],-10.f),10.f); int bi=0;
    for (int e=1;e<E_;e++){ float v=fminf(fmaxf(L[e],-10.f),10.f); if (v>best){best=v;bi=e;} }
    int g = h*E_+bi;
    if (which==0){ p.qsel[h*U_+u]=bi;  int pos=atomicAdd(&p.qcnt[g],1);  p.qlist[g*U_+pos]=u; }
    else         { p.kvsel[h*U_+u]=bi; int pos=atomicAdd(&p.kvcnt[g],1); p.kvlist[g*U_+pos]=u; }
  }
}

// ============================ MFMA GEMM (bf16 in, f32 acc) ============================
// MODE 0: mhc logits (K-chunked, partials)  1: kv-wide  2: q  3: pg2  4: y

template<int MODE>
__global__ __launch_bounds__(256) void k_mgemm(P p){
  const int n0 = blockIdx.x * 128;
  const int m0 = blockIdx.y * 128;
  const int g  = blockIdx.z;
  const int h  = g / E_;
  int K, NO, cnt;
  const int* list = nullptr;
  const u16* Bsrc;
  if (MODE==0){ K=1024; NO=1152; cnt=U_; Bsrc=p.Bt0; }
  else if (MODE==1){ K=1024; NO=1194; cnt=p.kvcnt[g]; list=p.kvlist+g*U_; Bsrc=p.Bt1+(size_t)g*1216*1024; }
  else if (MODE==2){ K=1024; NO=80;   cnt=p.qcnt[g];  list=p.qlist +g*U_; Bsrc=p.Bt2+(size_t)g*128*1024; }
  else if (MODE==3){ K=320;  NO=1024; cnt=p.kvcnt[g]; list=p.kvlist+g*U_; Bsrc=p.Bt3+(size_t)g*1024*320; }
  else { K=512; NO=1024; cnt=U_; Bsrc=p.Bt4; }
  if (m0 >= cnt) return;
  const int rows = min(128, cnt - m0);

  __shared__ u16 Asl[128*32];
  __shared__ u16 Bsl[128*32];
  __shared__ int toks[128];
  const int tid = threadIdx.x;
  if (tid < 128){
    if (MODE==0||MODE==4) toks[tid] = m0 + tid;
    else toks[tid] = (tid < rows) ? list[m0+tid] : list[m0];
  }
  __syncthreads();

  f32x4 acc[4][4];
  #pragma unroll
  for (int i=0;i<4;i++)
    #pragma unroll
    for (int j=0;j<4;j++) acc[i][j] = (f32x4)(0.f);

  const int lane = tid & 63, wv = tid >> 6;
  const int wr = (wv>>1)*64, wc = (wv&1)*64;
  const int l16 = lane & 15, kce = lane >> 4;

  for (int k0 = 0; k0 < K; k0 += 32){
    #pragma unroll
    for (int pass=0; pass<2; pass++){
      int m = (tid>>2) + pass*64;
      int kc4 = tid & 3;
      int ks = k0 + kc4*8;
      us8 av;
      if (MODE==1){
        int u = toks[m];
        av = *(const us8*)&p.he_kvB[((size_t)(h*U_+u))*1024 + ks];
      } else if (MODE==2){
        int u = toks[m];
        av = *(const us8*)&p.he_qB[((size_t)(h*U_+u))*1024 + ks];
      } else if (MODE==3){
        int u = toks[m];
        av = *(const us8*)&p.pgB[((size_t)(h*U_+u))*320 + ks];
      } else if (MODE==0){
        int u = toks[m];
        av = *(const us8*)&p.xb[(size_t)u*ND_ + g*1024 + ks];
      } else {
        int u = toks[m];
        const float* ap = p.attn + (size_t)u*CC_ + ks;
        const float* pp = p.pre_logit + (size_t)u*CC_ + ks;
        float4 a0 = *(const float4*)ap, a1 = *(const float4*)(ap+4);
        float4 q0 = *(const float4*)pp, q1 = *(const float4*)(pp+4);
        av[0]=f2b(a0.x*sigm(q0.x)); av[1]=f2b(a0.y*sigm(q0.y));
        av[2]=f2b(a0.z*sigm(q0.z)); av[3]=f2b(a0.w*sigm(q0.w));
        av[4]=f2b(a1.x*sigm(q1.x)); av[5]=f2b(a1.y*sigm(q1.y));
        av[6]=f2b(a1.z*sigm(q1.z)); av[7]=f2b(a1.w*sigm(q1.w));
      }
      *(us8*)&Asl[m*32 + kc4*8] = av;
    }
    #pragma unroll
    for (int pass=0; pass<2; pass++){
      int n = (tid>>2) + pass*64;
      int kc4 = tid & 3;
      int ks = k0 + kc4*8;
      int gn = n0 + n;
      us8 bv = (us8)((u16)0);
      if (MODE==1){ if (gn < 1216) bv = *(const us8*)&Bsrc[(size_t)gn*1024 + ks]; }
      else if (MODE==0){ bv = *(const us8*)&Bsrc[(size_t)gn*4096 + g*1024 + ks]; }
      else if (MODE==2){ bv = *(const us8*)&Bsrc[(size_t)gn*1024 + ks]; }
      else if (MODE==3){ bv = *(const us8*)&Bsrc[(size_t)gn*320 + ks]; }
      else { bv = *(const us8*)&Bsrc[(size_t)gn*512 + ks]; }
      *(us8*)&Bsl[n*32 + kc4*8] = bv;
    }
    __syncthreads();
    bhalf8 af[4], bf4[4];
    #pragma unroll
    for (int i=0;i<4;i++) af[i] = *(const bhalf8*)&Asl[(wr + i*16 + l16)*32 + kce*8];
    #pragma unroll
    for (int j=0;j<4;j++) bf4[j] = *(const bhalf8*)&Bsl[(wc + j*16 + l16)*32 + kce*8];
    #pragma unroll
    for (int i=0;i<4;i++)
      #pragma unroll
      for (int j=0;j<4;j++)
        acc[i][j] = __builtin_amdgcn_mfma_f32_16x16x32_bf16(af[i], bf4[j], acc[i][j], 0, 0, 0);
    __syncthreads();
  }

  #pragma unroll
  for (int i=0;i<4;i++){
    #pragma unroll
    for (int r=0;r<4;r++){
      int rl = wr + i*16 + kce*4 + r;
      if (rl >= rows) continue;
      int u = toks[rl];
      #pragma unroll
      for (int j=0;j<4;j++){
        int cg = n0 + wc + j*16 + l16;
        if (cg >= NO) continue;
        float v = acc[i][j][r];
        if (MODE==0){
          p.mhc_partial[(size_t)g*U_*1152 + (size_t)u*1152 + cg] = v;
        } else if (MODE==1){
          size_t base = (size_t)(h*U_+u);
          if (cg < 128)       p.kv_lin[base*128 + cg] = v;
          else if (cg < 231)  p.aup[base*DA_ + (cg-128)] = silu_(v);
          else if (cg < 334)  p.bup[base*DA_ + (cg-231)] = silu_(v);
          else if (cg < 846)  atomicAdd(&p.pre_logit[(size_t)u*CC_ + (cg-334)], v);
          else if (cg < 1162) p.pgB[base*320 + (cg-846)] = f2b(silu_(v));
          else if (cg < 1178) p.la_k[base*R_ + (cg-1162)] = silu_(v);
          else                p.la_v[base*R_ + (cg-1178)] = silu_(v);
        } else if (MODE==2){
          size_t base = (size_t)(h*U_+u);
          if (cg < 64) p.q_lin[base*64 + cg] = v;
          else         p.la_q[base*R_ + (cg-64)] = silu_(v);
        } else if (MODE==3){
          atomicAdd(&p.post_logit[(size_t)u*D_ + cg], v);
        } else {
          p.y[(size_t)u*D_ + cg] = v * sigm(p.post_logit[(size_t)u*D_ + cg]);
        }
      }
    }
  }
}

// ============================ downstream kernels ============================

DEV float lgread(const float* Pp, int j){
  const size_t S = (size_t)U_*1152;
  return Pp[j] + Pp[j+S] + Pp[j+2*S] + Pp[j+3*S];
}

__global__ void k_mhcsel(P p){
  int u = blockIdx.x;
  int tid = threadIdx.x;
  __shared__ float racc[8][16];
  __shared__ float pacc[8][4];
  if (tid < 8){
    int h = tid;
    const float* lg = p.mhc_partial + (size_t)u*1152;
    int kq = h*E_ + p.qsel[h*U_+u];
    for (int n=0;n<4;n++)
      p.Hpre_q[(size_t)(h*U_+u)*4 + n] = sigm(p.al_pre[kq]*lgread(lg,kq*24+n) + p.b_pre[kq*4+n]);
    int kk = h*E_ + p.kvsel[h*U_+u];
    for (int n=0;n<4;n++)
      p.Hpre_kv[(size_t)(h*U_+u)*4 + n] = sigm(p.al_pre[kk]*lgread(lg,kk*24+n) + p.b_pre[kk*4+n]);
    for (int n=0;n<4;n++)
      pacc[h][n] = 2.f*sigm(p.al_post[kk]*lgread(lg,kk*24+4+n) + p.b_post[kk*4+n]);
    float M[4][4];
    for (int n=0;n<4;n++)
      for (int m=0;m<4;m++)
        M[n][m] = expf(p.al_res[kk]*lgread(lg,kk*24+8+n*4+m) + p.b_res[kk*16+n*4+m]);
    for (int it=0; it<6; it++){
      for (int n=0;n<4;n++){ float s=M[n][0]+M[n][1]+M[n][2]+M[n][3]; float r=1.f/s;
        for(int m=0;m<4;m++) M[n][m]*=r; }
      for (int m=0;m<4;m++){ float s=M[0][m]+M[1][m]+M[2][m]+M[3][m]; float r=1.f/s;
        for(int n=0;n<4;n++) M[n][m]*=r; }
    }
    for (int n=0;n<4;n++) for (int m=0;m<4;m++) racc[h][n*4+m] = M[n][m];
  }
  __syncthreads();
  if (tid < 16){
    float s=0; for (int h=0;h<8;h++) s += racc[h][tid];
    p.Hres[(size_t)u*16 + tid] = s * 0.125f;
  }
  if (tid < 4){
    float s=0; for (int h=0;h<8;h++) s += pacc[h][tid];
    p.Hpost[(size_t)u*4 + tid] = s * 0.125f;
  }
}

__global__ void k_he(P p){
  int id = blockIdx.x;
  int path = id >> 13;
  int h = (id >> 10) & 7;
  int u = id & 1023;
  int b = u>>9, t = u&511;
  int sel = path ? p.kvsel[h*U_+u] : p.qsel[h*U_+u];
  int k = h*E_ + sel;
  const float* Hp = (path ? p.Hpre_kv : p.Hpre_q) + (size_t)(h*U_+u)*4;
  float w0=Hp[0], w1=Hp[1], w2=Hp[2], w3=Hp[3];
  float v[4];
  float ss = 0;
  int tid = threadIdx.x;
  #pragma unroll
  for (int j=0;j<4;j++){
    int d = tid + j*256;
    float s0 = p.stream[(((size_t)(b*N_+0)*T_)+t)*D_ + d];
    float s1 = p.stream[(((size_t)(b*N_+1)*T_)+t)*D_ + d];
    float s2 = p.stream[(((size_t)(b*N_+2)*T_)+t)*D_ + d];
    float s3 = p.stream[(((size_t)(b*N_+3)*T_)+t)*D_ + d];
    v[j] = w0*s0 + w1*s1 + w2*s2 + w3*s3;
    ss += v[j]*v[j];
  }
  __shared__ float sm[8];
  ss = block_reduce_sum(ss, sm);
  float sc = rsqrtf(ss/(float)D_ + 1e-8f);
  u16* out = (path ? p.he_kvB : p.he_qB) + (size_t)(h*U_+u)*D_;
  #pragma unroll
  for (int j=0;j<4;j++){
    int d = tid + j*256;
    out[d] = f2b(v[j]*sc*p.bn_w[(size_t)k*D_ + d]);
  }
}

// kv + q second stage merged: wave0 = k/v, wave1 = q
__global__ void k_stage2(P p){
  int id = blockIdx.x;
  int h = id >> 10, u = id & 1023;
  int t = u & 511;
  int kkv = h*E_ + p.kvsel[h*U_+u];
  size_t base = (size_t)(h*U_+u);
  __shared__ float s_au[DA_], s_bu[DA_], s_lk[R_], s_lv[R_], s_lq[R_], s_kl[64], s_vl[64], s_ql[64];
  int tid = threadIdx.x;
  if (tid < DA_){ s_au[tid] = p.aup[base*DA_+tid]; s_bu[tid] = p.bup[base*DA_+tid]; }
  if (tid < R_){ s_lk[tid] = p.la_k[base*R_+tid]; s_lv[tid] = p.la_v[base*R_+tid]; s_lq[tid] = p.la_q[base*R_+tid]; }
  if (tid >= 64 && tid < 128){
    s_kl[tid-64] = p.kv_lin[base*128 + (tid-64)];
    s_vl[tid-64] = p.kv_lin[base*128 + 64 + (tid-64)];
  }
  if (tid < 64) s_ql[tid] = p.q_lin[base*64 + tid];
  __syncthreads();
  {
    float acc = 0;
    const float* W = p.a_dn + (size_t)kkv*DA_*DKP_;
    for (int a=0;a<DA_;a++) acc += s_au[a]*W[a*DKP_ + tid];
    p.a_buf[base*DKP_ + tid] = sigm(acc);
  }
  if (tid == 0){
    float acc = 0;
    const float* W = p.b_dn + (size_t)kkv*DA_;
    for (int a=0;a<DA_;a++) acc += s_bu[a]*W[a];
    p.b_buf[base] = sigm(acc);
  }
  if (tid < 64){
    int o = tid;
    float lbk=0.f, lbv=0.f;
    for (int r=0;r<R_;r++){
      lbk += s_lk[r]*p.lB_k[((size_t)kkv*R_+r)*DK_ + o];
      lbv += s_lv[r]*p.lB_v[((size_t)kkv*R_+r)*DV_ + o];
    }
    float kl = s_kl[o] + lbk;
    float ss = kl*kl;
    for (int off=1; off<64; off<<=1) ss += __shfl_xor(ss, off, 64);
    float kp = kl * rsqrtf(ss + 1e-12f);
    float mu = softplus_(kp);
    float ph = (float)t * p.freqs[o] - 6.2831855f * sigm(p.pope_delta[o]);
    p.k_buf[base*DKP_ + o]      = mu * cosf(ph);
    p.k_buf[base*DKP_ + 64 + o] = mu * sinf(ph);
    p.v_buf[base*DV_ + o] = s_vl[o] + lbv;
  } else {
    int o = tid - 64;
    int sel = p.qsel[h*U_+u];
    if (sel == 0){
      p.q_buf[base*DKP_ + o] = 0.f;
      p.q_buf[base*DKP_ + 64 + o] = 0.f;
    } else {
      int kq = h*E_ + sel;
      float lbq = 0.f;
      for (int r=0;r<R_;r++) lbq += s_lq[r]*p.lB_q[((size_t)kq*R_+r)*DK_+o];
      float ql = s_ql[o] + lbq;
      float ss = ql*ql;
      for (int off=1; off<64; off<<=1) ss += __shfl_xor(ss, off, 64);
      float qp = ql*rsqrtf(ss + 1e-12f);
      float mu = softplus_(qp);
      float ph = (float)t * p.freqs[o];
      p.q_buf[base*DKP_ + o]      = mu*cosf(ph);
      p.q_buf[base*DKP_ + 64 + o] = mu*sinf(ph);
    }
  }
}

// ---- KDA delta-rule scan: 256 thr, SGPR k/a, LDS only for q + partials ----
__global__ __launch_bounds__(256) void k_scan(P p){
  const int h = blockIdx.x >> 1, b = blockIdx.x & 1;
  const int tid = threadIdx.x;
  const int e = tid & 63;
  const int qd = __builtin_amdgcn_readfirstlane(tid >> 6);
  const int d0 = qd * 32;
  const size_t hb = (size_t)(h*U_ + b*T_);
  float s[32];
  #pragma unroll
  for (int i=0;i<32;i++) s[i]=0.f;
  __shared__ float sq[2][128];
  __shared__ float part[2][4][64];
  __shared__ float part2[4][64];
  float rq = (tid<128) ? p.q_buf[hb*128 + tid] : 0.f;
  if (tid<128) sq[0][tid] = rq;
  rq = (tid<128) ? p.q_buf[(hb+1)*128 + tid] : 0.f;
  __syncthreads();
  for (int t=0;t<T_;t++){
    const int bb = t&1;
    const size_t base = hb + t;
    // wave-uniform slices -> scalar loads
    const float* kp = p.k_buf + base*128 + d0;
    const float* ap = p.a_buf + base*128 + d0;
    float kr[32], ar[32];
    #pragma unroll
    for (int i=0;i<32;i++){ kr[i]=kp[i]; ar[i]=ap[i]; }
    float bs = p.b_buf[base];
    float vv = p.v_buf[base*64 + e];
    float pa = 0.f;
    #pragma unroll
    for (int i=0;i<32;i++) pa += (ar[i]*s[i])*kr[i];
    part[bb][qd][e] = pa;
    __syncthreads();                                   // B
    float w = vv - (part[bb][0][e]+part[bb][1][e]+part[bb][2][e]+part[bb][3][e]);
    float bw = bs * w;
    float o = 0.f;
    #pragma unroll
    for (int i=0;i<32;i++){
      s[i] = ar[i]*s[i] + bw*kr[i];
      o += sq[bb][d0+i] * s[i];
    }
    if (tid < 128) sq[bb^1][tid] = rq;                 // stage q for t+1
    part2[qd][e] = o;
    __syncthreads();                                   // C
    if (tid < 64){
      float r = part2[0][tid]+part2[1][tid]+part2[2][tid]+part2[3][tid];
      p.attn[(size_t)(b*T_+t)*CC_ + h*64 + tid] = r;
    }
    if (tid < 128 && t+2 < T_) rq = p.q_buf[(hb+t+2)*128 + tid];
  }
}

__global__ void k_final(P p){
  int u = blockIdx.x, b=u>>9, t=u&511;
  __shared__ float hr[16], hp[4];
  if (threadIdx.x < 16) hr[threadIdx.x] = p.Hres[(size_t)u*16+threadIdx.x];
  if (threadIdx.x < 4)  hp[threadIdx.x] = p.Hpost[(size_t)u*4+threadIdx.x];
  __syncthreads();
  for (int d = threadIdx.x; d < D_; d += 256){
    float yv = p.y[(size_t)u*D_ + d];
    float sm0 = p.stream[(((size_t)(b*N_+0)*T_)+t)*D_ + d];
    float sm1 = p.stream[(((size_t)(b*N_+1)*T_)+t)*D_ + d];
    float sm2 = p.stream[(((size_t)(b*N_+2)*T_)+t)*D_ + d];
    float sm3 = p.stream[(((size_t)(b*N_+3)*T_)+t)*D_ + d];
    #pragma unroll
    for (int n=0;n<4;n++){
      float v = hr[n*4+0]*sm0 + hr[n*4+1]*sm1 + hr[n*4+2]*sm2 + hr[n*4+3]*sm3 + hp[n]*yv;
      p.out[(((size_t)(b*N_+n)*T_)+t)*D_ + d] = v;
    }
  }
}

// ============================ host launch ============================

extern "C" void kernel_launch(void* const* d_in, const int* in_sizes, int n_in,
                              void* d_out, int out_size, void* d_ws, size_t ws_size,
                              hipStream_t stream){
  P p;
  p.stream = (const float*)d_in[0];
  p.freqs = (const float*)d_in[1];
  p.pope_delta = (const float*)d_in[2];
  p.W_q = (const float*)d_in[3]; p.W_k = (const float*)d_in[4]; p.W_v = (const float*)d_in[5];
  p.q_rw = (const float*)d_in[6]; p.kv_rw = (const float*)d_in[7];
  p.lA_q = (const float*)d_in[8];  p.lB_q = (const float*)d_in[9];
  p.lA_k = (const float*)d_in[10]; p.lB_k = (const float*)d_in[11];
  p.lA_v = (const float*)d_in[12]; p.lB_v = (const float*)d_in[13];
  p.a_up = (const float*)d_in[14]; p.a_dn = (const float*)d_in[15];
  p.b_up = (const float*)d_in[16]; p.b_dn = (const float*)d_in[17];
  p.mhc_norm = (const float*)d_in[18];
  p.phi_pre = (const float*)d_in[19]; p.phi_post = (const float*)d_in[20]; p.phi_res = (const float*)d_in[21];
  p.b_pre = (const float*)d_in[22]; p.b_post = (const float*)d_in[23]; p.b_res = (const float*)d_in[24];
  p.al_pre = (const float*)d_in[25]; p.al_post = (const float*)d_in[26]; p.al_res = (const float*)d_in[27];
  p.bn_w = (const float*)d_in[28];
  p.W_pre = (const float*)d_in[29]; p.W_o = (const float*)d_in[30];
  p.W_pg1 = (const float*)d_in[31]; p.W_pg2 = (const float*)d_in[32];
  p.out = (float*)d_out;

  char* w = (char*)d_ws;
  size_t off = 0;
  auto alloc = [&](size_t bytes)->void*{
    void* r = w + off;
    off = (off + bytes + 255) & ~(size_t)255;
    return r;
  };
  p.qsel   = (int*)alloc(H_*U_*4);
  p.kvsel  = (int*)alloc(H_*U_*4);
  p.qcnt   = (int*)alloc(HE_*4);
  p.kvcnt  = (int*)alloc(HE_*4);
  p.qlist  = (int*)alloc((size_t)HE_*U_*4);
  p.kvlist = (int*)alloc((size_t)HE_*U_*4);
  p.scale  = (float*)alloc(U_*4);
  p.mhc_partial = (float*)alloc((size_t)4*U_*1152*4);
  p.Hpre_q  = (float*)alloc((size_t)H_*U_*4*4);
  p.Hpre_kv = (float*)alloc((size_t)H_*U_*4*4);
  p.Hres    = (float*)alloc((size_t)U_*16*4);
  p.Hpost   = (float*)alloc((size_t)U_*4*4);
  p.kv_lin  = (float*)alloc((size_t)H_*U_*128*4);
  p.aup     = (float*)alloc((size_t)H_*U_*DA_*4);
  p.bup     = (float*)alloc((size_t)H_*U_*DA_*4);
  p.pre_logit  = (float*)alloc((size_t)U_*CC_*4);
  p.post_logit = (float*)alloc((size_t)U_*D_*4);
  p.la_k    = (float*)alloc((size_t)H_*U_*R_*4);
  p.la_v    = (float*)alloc((size_t)H_*U_*R_*4);
  p.la_q    = (float*)alloc((size_t)H_*U_*R_*4);
  p.q_lin   = (float*)alloc((size_t)H_*U_*64*4);
  p.a_buf   = (float*)alloc((size_t)H_*U_*DKP_*4);
  p.b_buf   = (float*)alloc((size_t)H_*U_*4);
  p.q_buf   = (float*)alloc((size_t)H_*U_*DKP_*4);
  p.k_buf   = (float*)alloc((size_t)H_*U_*DKP_*4);
  p.v_buf   = (float*)alloc((size_t)H_*U_*DV_*4);
  p.attn    = (float*)alloc((size_t)U_*CC_*4);
  p.y       = (float*)alloc((size_t)U_*D_*4);
  p.xb      = (u16*)alloc((size_t)U_*ND_*2);
  p.he_kvB = (u16*)alloc((size_t)H_*U_*D_*2);
  p.he_qB  = (u16*)alloc((size_t)H_*U_*D_*2);
  p.pgB    = (u16*)alloc((size_t)H_*U_*320*2);
  p.Bt0    = (u16*)alloc((size_t)1152*4096*2);
  p.Bt1    = (u16*)alloc((size_t)HE_*1216*1024*2);
  p.Bt2    = (u16*)alloc((size_t)HE_*128*1024*2);
  p.Bt3    = (u16*)alloc((size_t)HE_*1024*320*2);
  p.Bt4    = (u16*)alloc((size_t)1024*512*2);
  if (off > ws_size) return;

  hipMemsetAsync(p.qcnt, 0, HE_*4, stream);
  hipMemsetAsync(p.kvcnt, 0, HE_*4, stream);
  hipMemsetAsync(p.pre_logit, 0, (size_t)U_*CC_*4, stream);
  hipMemsetAsync(p.post_logit, 0, (size_t)U_*D_*4, stream);
  hipMemsetAsync(p.pgB, 0, (size_t)H_*U_*320*2, stream);
  hipMemsetAsync(p.Bt2, 0, (size_t)HE_*128*1024*2, stream);

  k_prep0<<<1152,256,0,stream>>>(p);
  k_prep1d<<<dim3(150,48),256,0,stream>>>(p);
  size_t b1s = (size_t)1216*1024;
  k_prept<<<dim3(32, 4,48),256,0,stream>>>(p.a_up,  (long)1024*DA_, DA_, DA_, p.Bt1+ 128*1024, b1s, 1024, 1024, 1024);
  k_prept<<<dim3(32, 4,48),256,0,stream>>>(p.b_up,  (long)1024*DA_, DA_, DA_, p.Bt1+ 231*1024, b1s, 1024, 1024, 1024);
  k_prept<<<dim3(32,16,48),256,0,stream>>>(p.W_pre, (long)1024*CC_, CC_, CC_, p.Bt1+ 334*1024, b1s, 1024, 1024, 1024);
  k_prept<<<dim3(32,10,48),256,0,stream>>>(p.W_pg1, (long)1024*DPG_,DPG_,DPG_,p.Bt1+ 846*1024, b1s, 1024, 1024, 1024);
  k_prept<<<dim3(32, 1,48),256,0,stream>>>(p.lA_k,  (long)1024*R_,  R_,  R_,  p.Bt1+1162*1024, b1s, 1024, 1024, 1024);
  k_prept<<<dim3(32, 1,48),256,0,stream>>>(p.lA_v,  (long)1024*R_,  R_,  R_,  p.Bt1+1178*1024, b1s, 1024, 1024, 1024);
  k_prep2d<<<dim3(64,48),256,0,stream>>>(p);
  k_prept<<<dim3(32, 1,48),256,0,stream>>>(p.lA_q,  (long)1024*R_,  R_,  R_,  p.Bt2+  64*1024, (long)128*1024, 1024, 1024, 1024);
  k_prept<<<dim3(10,32,48),256,0,stream>>>(p.W_pg2, (long)DPG_*1024,1024,1024,p.Bt3,           (long)1024*320,  320,  320,  316);
  k_prep4<<<1024,256,0,stream>>>(p);

  k_route<<<U_,256,0,stream>>>(p);
  k_mgemm<0><<<dim3(9,8,4),256,0,stream>>>(p);
  k_mhcsel<<<U_,64,0,stream>>>(p);
  k_he<<<2*H_*U_,256,0,stream>>>(p);
  k_mgemm<1><<<dim3(10,8,48),256,0,stream>>>(p);
  k_mgemm<2><<<dim3(1,8,48),256,0,stream>>>(p);
  k_stage2<<<H_*U_,128,0,stream>>>(p);
  k_mgemm<3><<<dim3(8,8,48),256,0,stream>>>(p);
  k_scan<<<16,256,0,stream>>>(p);
  k_mgemm<4><<<dim3(8,8,1),256,0,stream>>>(p);
  k_final<<<U_,256,0,stream>>>(p);
}

// Round 5
// 1540.041 us; speedup vs baseline: 1.0534x; 1.0534x over previous
//
#include <hip/hip_runtime.h>
#include <math.h>

#define DEV static __device__ __forceinline__

// ---- problem constants ----
#define B_   2
#define N_   4
#define T_   512
#define D_   1024
#define DK_  64
#define H_   8
#define E_   6
#define DV_  64
#define DKP_ 128
#define HE_  48
#define R_   16
#define DA_  103
#define CC_  512
#define DPG_ 316
#define ND_  4096
#define U_   1024      // B*T tokens

typedef unsigned short u16;
typedef __attribute__((ext_vector_type(8))) unsigned short us8;
typedef __attribute__((ext_vector_type(8))) short bhalf8;
typedef __attribute__((ext_vector_type(4))) float f32x4;

struct P {
  // inputs
  const float *stream, *freqs, *pope_delta;
  const float *W_q, *W_k, *W_v, *q_rw, *kv_rw;
  const float *lA_q, *lB_q, *lA_k, *lB_k, *lA_v, *lB_v;
  const float *a_up, *a_dn, *b_up, *b_dn;
  const float *mhc_norm, *phi_pre, *phi_post, *phi_res;
  const float *b_pre, *b_post, *b_res, *al_pre, *al_post, *al_res;
  const float *bn_w, *W_pre, *W_o, *W_pg1, *W_pg2;
  // workspace
  int *qsel, *kvsel, *qcnt, *kvcnt, *qlist, *kvlist;
  float *scale, *mhc_partial;
  float *Hpre_q, *Hpre_kv, *Hres, *Hpost;
  float *kv_lin, *aup, *bup, *pre_logit, *post_logit;
  float *la_k, *la_v, *la_q, *q_lin;
  float *a_buf, *b_buf, *q_buf, *k_buf, *v_buf;
  float *attn, *y;
  float *out;
  u16 *xb;                       // bf16 rms-scaled x, (U, ND)
  u16 *he_kvB, *he_qB, *pgB;
  u16 *Bt0, *Bt1, *Bt2, *Bt3, *Bt4;
};

DEV float sigm(float x){ return 1.f/(1.f+expf(-x)); }
DEV float softplus_(float x){ return x>0.f ? x+log1pf(expf(-x)) : log1pf(expf(x)); }
DEV float silu_(float x){ return x*sigm(x); }
DEV u16 f2b(float x){ unsigned u = __float_as_uint(x); u += 0x7FFFu + ((u>>16)&1u); return (u16)(u>>16); }

template<int CTRL>
DEV float dppq(float x){
  return __int_as_float(__builtin_amdgcn_mov_dpp(__float_as_int(x), CTRL, 0xF, 0xF, true));
}

DEV float block_reduce_sum(float v, float* sm){
  __syncthreads();
  int lane = threadIdx.x & 63, w = threadIdx.x >> 6;
  for (int off=32; off; off>>=1) v += __shfl_down(v, off, 64);
  if (lane==0) sm[w] = v;
  __syncthreads();
  if (threadIdx.x == 0){
    float s = 0; int nw = blockDim.x >> 6;
    for (int i=0;i<nw;i++) s += sm[i];
    sm[0] = s;
  }
  __syncthreads();
  return sm[0];
}

// ============================ prep kernels (bf16 B panels) ============================

__global__ void k_prep0(P p){
  int j = blockIdx.x; int k = j/24, r = j%24;
  const float* src;
  if (r < 4)      src = p.phi_pre  + (size_t)(k*4+r)*ND_;
  else if (r < 8) src = p.phi_post + (size_t)(k*4+(r-4))*ND_;
  else            src = p.phi_res  + (size_t)(k*16+(r-8))*ND_;
  const float* mn = p.mhc_norm + (size_t)k*ND_;
  u16* d = p.Bt0 + (size_t)j*ND_;
  for (int i = threadIdx.x; i < ND_; i += 256) d[i] = f2b(src[i]*mn[i]);
}

__global__ void k_prep1d(P p){
  int r = blockIdx.x, g = blockIdx.y, h = g/E_;
  u16* drow = p.Bt1 + (size_t)g*1216*1024 + (size_t)(r<128 ? r : 1194 + (r-128))*1024;
  const float* srow = (r<64) ? (p.W_k + ((size_t)h*64 + r)*1024)
                   : (r<128) ? (p.W_v + ((size_t)h*64 + (r-64))*1024) : nullptr;
  for (int k2 = threadIdx.x; k2 < 1024; k2 += 256)
    drow[k2] = (r<128) ? f2b(srow[k2]) : (u16)0;
}

__global__ void k_prep2d(P p){
  int r = blockIdx.x, g = blockIdx.y, h = g/E_;
  u16* drow = p.Bt2 + (size_t)g*128*1024 + (size_t)r*1024;
  const float* srow = p.W_q + ((size_t)h*64 + r)*1024;
  for (int k2 = threadIdx.x; k2 < 1024; k2 += 256) drow[k2] = f2b(srow[k2]);
}

__global__ void k_prep4(P p){
  int r = blockIdx.x;
  u16* drow = p.Bt4 + (size_t)r*512;
  const float* srow = p.W_o + (size_t)r*512;
  for (int c = threadIdx.x; c < 512; c += 256) drow[c] = f2b(srow[c]);
}

__global__ void k_prept(const float* src, long sstride, int ld, int ncols,
                        u16* dst, long dstride, int dld, int K, int Ksrc){
  __shared__ float t[32][33];
  const float* S = src + (size_t)blockIdx.z*sstride;
  u16* Dp = dst + (size_t)blockIdx.z*dstride;
  int k0 = blockIdx.x*32, c0 = blockIdx.y*32;
  int tx = threadIdx.x & 31, ty = threadIdx.x >> 5;
  #pragma unroll
  for (int i=0;i<32;i+=8){
    int k = k0+ty+i, c = c0+tx;
    t[ty+i][tx] = (k < Ksrc && c < ncols) ? S[(size_t)k*ld + c] : 0.f;
  }
  __syncthreads();
  #pragma unroll
  for (int i=0;i<32;i+=8){
    int c = c0+ty+i, k = k0+tx;
    if (c < ncols && k < K) Dp[(size_t)c*dld + k] = f2b(t[tx][ty+i]);
  }
}

// ============================ routing + rms-scale + bf16 x ============================

__global__ void k_route(P p){
  int u = blockIdx.x, b = u>>9, t = u&511;
  __shared__ float ri[D_];
  __shared__ float lg[2][HE_];
  __shared__ float sm[8];
  int tid = threadIdx.x;
  float sv[4][4]; float ss = 0.f;
  #pragma unroll
  for (int j=0;j<4;j++){
    int d = tid + j*256;
    float acc = 0;
    #pragma unroll
    for (int n = 0; n < 4; n++){
      float v = p.stream[(((size_t)(b*N_+n)*T_)+t)*D_ + d];
      sv[j][n] = v; acc += v; ss += v*v;
    }
    ri[d] = acc * 0.25f;
  }
  ss = block_reduce_sum(ss, sm);
  float sc = rsqrtf(ss/(float)ND_ + 1e-8f);
  if (tid==0) p.scale[u] = sc;
  #pragma unroll
  for (int j=0;j<4;j++){
    int d = tid + j*256;
    #pragma unroll
    for (int n=0;n<4;n++)
      p.xb[(size_t)u*ND_ + n*D_ + d] = f2b(sv[j][n]*sc);
  }
  int lane = tid & 63, wv = tid >> 6;
  for (int j = wv; j < 2*HE_; j += 4){
    const float* w = (j < HE_ ? p.q_rw : p.kv_rw) + (size_t)(j % HE_)*D_;
    float acc = 0;
    for (int d = lane; d < D_; d += 64) acc += ri[d]*w[d];
    for (int off=32; off; off>>=1) acc += __shfl_down(acc, off, 64);
    if (lane==0) lg[j/HE_][j%HE_] = acc;
  }
  __syncthreads();
  if (tid < 16){
    int h = tid & 7, which = tid >> 3;
    const float* L = lg[which] + h*E_;
    float best = fminf(fmaxf(L[0],-10.f),10.f); int bi=0;
    for (int e=1;e<E_;e++){ float v=fminf(fmaxf(L[e],-10.f),10.f); if (v>best){best=v;bi=e;} }
    int g = h*E_+bi;
    if (which==0){ p.qsel[h*U_+u]=bi;  int pos=atomicAdd(&p.qcnt[g],1);  p.qlist[g*U_+pos]=u; }
    else         { p.kvsel[h*U_+u]=bi; int pos=atomicAdd(&p.kvcnt[g],1); p.kvlist[g*U_+pos]=u; }
  }
}

// ============================ MFMA GEMM (bf16 in, f32 acc) ============================
// MODE 0: mhc logits (K-chunked, partials)  1: kv-wide  2: q  3: pg2  4: y

template<int MODE>
__global__ __launch_bounds__(256) void k_mgemm(P p){
  const int n0 = blockIdx.x * 128;
  const int m0 = blockIdx.y * 128;
  const int g  = blockIdx.z;
  const int h  = g / E_;
  int K, NO, cnt;
  const int* list = nullptr;
  const u16* Bsrc;
  if (MODE==0){ K=1024; NO=1152; cnt=U_; Bsrc=p.Bt0; }
  else if (MODE==1){ K=1024; NO=1194; cnt=p.kvcnt[g]; list=p.kvlist+g*U_; Bsrc=p.Bt1+(size_t)g*1216*1024; }
  else if (MODE==2){ K=1024; NO=80;   cnt=p.qcnt[g];  list=p.qlist +g*U_; Bsrc=p.Bt2+(size_t)g*128*1024; }
  else if (MODE==3){ K=320;  NO=1024; cnt=p.kvcnt[g]; list=p.kvlist+g*U_; Bsrc=p.Bt3+(size_t)g*1024*320; }
  else { K=512; NO=1024; cnt=U_; Bsrc=p.Bt4; }
  if (m0 >= cnt) return;
  const int rows = min(128, cnt - m0);

  __shared__ u16 Asl[128*32];
  __shared__ u16 Bsl[128*32];
  __shared__ int toks[128];
  const int tid = threadIdx.x;
  if (tid < 128){
    if (MODE==0||MODE==4) toks[tid] = m0 + tid;
    else toks[tid] = (tid < rows) ? list[m0+tid] : list[m0];
  }
  __syncthreads();

  f32x4 acc[4][4];
  #pragma unroll
  for (int i=0;i<4;i++)
    #pragma unroll
    for (int j=0;j<4;j++) acc[i][j] = (f32x4)(0.f);

  const int lane = tid & 63, wv = tid >> 6;
  const int wr = (wv>>1)*64, wc = (wv&1)*64;
  const int l16 = lane & 15, kce = lane >> 4;

  for (int k0 = 0; k0 < K; k0 += 32){
    #pragma unroll
    for (int pass=0; pass<2; pass++){
      int m = (tid>>2) + pass*64;
      int kc4 = tid & 3;
      int ks = k0 + kc4*8;
      us8 av;
      if (MODE==1){
        int u = toks[m];
        av = *(const us8*)&p.he_kvB[((size_t)(h*U_+u))*1024 + ks];
      } else if (MODE==2){
        int u = toks[m];
        av = *(const us8*)&p.he_qB[((size_t)(h*U_+u))*1024 + ks];
      } else if (MODE==3){
        int u = toks[m];
        av = *(const us8*)&p.pgB[((size_t)(h*U_+u))*320 + ks];
      } else if (MODE==0){
        int u = toks[m];
        av = *(const us8*)&p.xb[(size_t)u*ND_ + g*1024 + ks];
      } else {
        int u = toks[m];
        const float* ap = p.attn + (size_t)u*CC_ + ks;
        const float* pp = p.pre_logit + (size_t)u*CC_ + ks;
        float4 a0 = *(const float4*)ap, a1 = *(const float4*)(ap+4);
        float4 q0 = *(const float4*)pp, q1 = *(const float4*)(pp+4);
        av[0]=f2b(a0.x*sigm(q0.x)); av[1]=f2b(a0.y*sigm(q0.y));
        av[2]=f2b(a0.z*sigm(q0.z)); av[3]=f2b(a0.w*sigm(q0.w));
        av[4]=f2b(a1.x*sigm(q1.x)); av[5]=f2b(a1.y*sigm(q1.y));
        av[6]=f2b(a1.z*sigm(q1.z)); av[7]=f2b(a1.w*sigm(q1.w));
      }
      *(us8*)&Asl[m*32 + kc4*8] = av;
    }
    #pragma unroll
    for (int pass=0; pass<2; pass++){
      int n = (tid>>2) + pass*64;
      int kc4 = tid & 3;
      int ks = k0 + kc4*8;
      int gn = n0 + n;
      us8 bv = (us8)((u16)0);
      if (MODE==1){ if (gn < 1216) bv = *(const us8*)&Bsrc[(size_t)gn*1024 + ks]; }
      else if (MODE==0){ bv = *(const us8*)&Bsrc[(size_t)gn*4096 + g*1024 + ks]; }
      else if (MODE==2){ bv = *(const us8*)&Bsrc[(size_t)gn*1024 + ks]; }
      else if (MODE==3){ bv = *(const us8*)&Bsrc[(size_t)gn*320 + ks]; }
      else { bv = *(const us8*)&Bsrc[(size_t)gn*512 + ks]; }
      *(us8*)&Bsl[n*32 + kc4*8] = bv;
    }
    __syncthreads();
    bhalf8 af[4], bf4[4];
    #pragma unroll
    for (int i=0;i<4;i++) af[i] = *(const bhalf8*)&Asl[(wr + i*16 + l16)*32 + kce*8];
    #pragma unroll
    for (int j=0;j<4;j++) bf4[j] = *(const bhalf8*)&Bsl[(wc + j*16 + l16)*32 + kce*8];
    #pragma unroll
    for (int i=0;i<4;i++)
      #pragma unroll
      for (int j=0;j<4;j++)
        acc[i][j] = __builtin_amdgcn_mfma_f32_16x16x32_bf16(af[i], bf4[j], acc[i][j], 0, 0, 0);
    __syncthreads();
  }

  #pragma unroll
  for (int i=0;i<4;i++){
    #pragma unroll
    for (int r=0;r<4;r++){
      int rl = wr + i*16 + kce*4 + r;
      if (rl >= rows) continue;
      int u = toks[rl];
      #pragma unroll
      for (int j=0;j<4;j++){
        int cg = n0 + wc + j*16 + l16;
        if (cg >= NO) continue;
        float v = acc[i][j][r];
        if (MODE==0){
          p.mhc_partial[(size_t)g*U_*1152 + (size_t)u*1152 + cg] = v;
        } else if (MODE==1){
          size_t base = (size_t)(h*U_+u);
          if (cg < 128)       p.kv_lin[base*128 + cg] = v;
          else if (cg < 231)  p.aup[base*DA_ + (cg-128)] = silu_(v);
          else if (cg < 334)  p.bup[base*DA_ + (cg-231)] = silu_(v);
          else if (cg < 846)  atomicAdd(&p.pre_logit[(size_t)u*CC_ + (cg-334)], v);
          else if (cg < 1162) p.pgB[base*320 + (cg-846)] = f2b(silu_(v));
          else if (cg < 1178) p.la_k[base*R_ + (cg-1162)] = silu_(v);
          else                p.la_v[base*R_ + (cg-1178)] = silu_(v);
        } else if (MODE==2){
          size_t base = (size_t)(h*U_+u);
          if (cg < 64) p.q_lin[base*64 + cg] = v;
          else         p.la_q[base*R_ + (cg-64)] = silu_(v);
        } else if (MODE==3){
          atomicAdd(&p.post_logit[(size_t)u*D_ + cg], v);
        } else {
          p.y[(size_t)u*D_ + cg] = v * sigm(p.post_logit[(size_t)u*D_ + cg]);
        }
      }
    }
  }
}

// ============================ downstream kernels ============================

DEV float lgread(const float* Pp, int j){
  const size_t S = (size_t)U_*1152;
  return Pp[j] + Pp[j+S] + Pp[j+2*S] + Pp[j+3*S];
}

__global__ void k_mhcsel(P p){
  int u = blockIdx.x;
  int tid = threadIdx.x;
  __shared__ float racc[8][16];
  __shared__ float pacc[8][4];
  if (tid < 8){
    int h = tid;
    const float* lg = p.mhc_partial + (size_t)u*1152;
    int kq = h*E_ + p.qsel[h*U_+u];
    for (int n=0;n<4;n++)
      p.Hpre_q[(size_t)(h*U_+u)*4 + n] = sigm(p.al_pre[kq]*lgread(lg,kq*24+n) + p.b_pre[kq*4+n]);
    int kk = h*E_ + p.kvsel[h*U_+u];
    for (int n=0;n<4;n++)
      p.Hpre_kv[(size_t)(h*U_+u)*4 + n] = sigm(p.al_pre[kk]*lgread(lg,kk*24+n) + p.b_pre[kk*4+n]);
    for (int n=0;n<4;n++)
      pacc[h][n] = 2.f*sigm(p.al_post[kk]*lgread(lg,kk*24+4+n) + p.b_post[kk*4+n]);
    float M[4][4];
    for (int n=0;n<4;n++)
      for (int m=0;m<4;m++)
        M[n][m] = expf(p.al_res[kk]*lgread(lg,kk*24+8+n*4+m) + p.b_res[kk*16+n*4+m]);
    for (int it=0; it<6; it++){
      for (int n=0;n<4;n++){ float s=M[n][0]+M[n][1]+M[n][2]+M[n][3]; float r=1.f/s;
        for(int m=0;m<4;m++) M[n][m]*=r; }
      for (int m=0;m<4;m++){ float s=M[0][m]+M[1][m]+M[2][m]+M[3][m]; float r=1.f/s;
        for(int n=0;n<4;n++) M[n][m]*=r; }
    }
    for (int n=0;n<4;n++) for (int m=0;m<4;m++) racc[h][n*4+m] = M[n][m];
  }
  __syncthreads();
  if (tid < 16){
    float s=0; for (int h=0;h<8;h++) s += racc[h][tid];
    p.Hres[(size_t)u*16 + tid] = s * 0.125f;
  }
  if (tid < 4){
    float s=0; for (int h=0;h<8;h++) s += pacc[h][tid];
    p.Hpost[(size_t)u*4 + tid] = s * 0.125f;
  }
}

// fused h_e: one block per token u, all 16 (path,h) rows; stream read once
__global__ __launch_bounds__(256) void k_he2(P p){
  int u = blockIdx.x, b = u>>9, t = u&511;
  int tid = threadIdx.x;
  int lane = tid & 63, wv = tid >> 6;
  __shared__ float wts[16][4];
  __shared__ int   ksl[16];
  __shared__ float red[16][4];
  __shared__ float scl[16];
  if (tid < 16){
    int path = tid >> 3, h = tid & 7;
    int sel = path ? p.kvsel[h*U_+u] : p.qsel[h*U_+u];
    ksl[tid] = h*E_ + sel;
    const float* Hp = (path ? p.Hpre_kv : p.Hpre_q) + (size_t)(h*U_+u)*4;
    #pragma unroll
    for (int n=0;n<4;n++) wts[tid][n] = Hp[n];
  }
  __syncthreads();
  float s[4][4];
  #pragma unroll
  for (int j=0;j<4;j++){
    int d = tid + j*256;
    #pragma unroll
    for (int n=0;n<4;n++)
      s[j][n] = p.stream[(((size_t)(b*N_+n)*T_)+t)*D_ + d];
  }
  float ssl[16];
  #pragma unroll
  for (int c=0;c<16;c++){
    float w0=wts[c][0], w1=wts[c][1], w2=wts[c][2], w3=wts[c][3];
    float acc = 0;
    #pragma unroll
    for (int j=0;j<4;j++){
      float v = w0*s[j][0] + w1*s[j][1] + w2*s[j][2] + w3*s[j][3];
      acc += v*v;
    }
    ssl[c] = acc;
  }
  #pragma unroll
  for (int c=0;c<16;c++){
    float v = ssl[c];
    for (int off=32; off; off>>=1) v += __shfl_down(v, off, 64);
    if (lane==0) red[c][wv] = v;
  }
  __syncthreads();
  if (tid < 16){
    float ssum = red[tid][0]+red[tid][1]+red[tid][2]+red[tid][3];
    scl[tid] = rsqrtf(ssum/(float)D_ + 1e-8f);
  }
  __syncthreads();
  #pragma unroll
  for (int c=0;c<16;c++){
    float w0=wts[c][0], w1=wts[c][1], w2=wts[c][2], w3=wts[c][3];
    float sc = scl[c];
    int k = ksl[c];
    int h = c & 7;
    u16* out = (c>=8 ? p.he_kvB : p.he_qB) + (size_t)(h*U_+u)*D_;
    #pragma unroll
    for (int j=0;j<4;j++){
      int d = tid + j*256;
      float v = w0*s[j][0] + w1*s[j][1] + w2*s[j][2] + w3*s[j][3];
      out[d] = f2b(v*sc*p.bn_w[(size_t)k*D_ + d]);
    }
  }
}

// kv + q second stage merged: wave0 = k/v, wave1 = q
__global__ void k_stage2(P p){
  int id = blockIdx.x;
  int h = id >> 10, u = id & 1023;
  int t = u & 511;
  int kkv = h*E_ + p.kvsel[h*U_+u];
  size_t base = (size_t)(h*U_+u);
  __shared__ float s_au[DA_], s_bu[DA_], s_lk[R_], s_lv[R_], s_lq[R_], s_kl[64], s_vl[64], s_ql[64];
  int tid = threadIdx.x;
  if (tid < DA_){ s_au[tid] = p.aup[base*DA_+tid]; s_bu[tid] = p.bup[base*DA_+tid]; }
  if (tid < R_){ s_lk[tid] = p.la_k[base*R_+tid]; s_lv[tid] = p.la_v[base*R_+tid]; s_lq[tid] = p.la_q[base*R_+tid]; }
  if (tid >= 64 && tid < 128){
    s_kl[tid-64] = p.kv_lin[base*128 + (tid-64)];
    s_vl[tid-64] = p.kv_lin[base*128 + 64 + (tid-64)];
  }
  if (tid < 64) s_ql[tid] = p.q_lin[base*64 + tid];
  __syncthreads();
  {
    float acc = 0;
    const float* W = p.a_dn + (size_t)kkv*DA_*DKP_;
    for (int a=0;a<DA_;a++) acc += s_au[a]*W[a*DKP_ + tid];
    p.a_buf[base*DKP_ + tid] = sigm(acc);
  }
  if (tid == 0){
    float acc = 0;
    const float* W = p.b_dn + (size_t)kkv*DA_;
    for (int a=0;a<DA_;a++) acc += s_bu[a]*W[a];
    p.b_buf[base] = sigm(acc);
  }
  if (tid < 64){
    int o = tid;
    float lbk=0.f, lbv=0.f;
    for (int r=0;r<R_;r++){
      lbk += s_lk[r]*p.lB_k[((size_t)kkv*R_+r)*DK_ + o];
      lbv += s_lv[r]*p.lB_v[((size_t)kkv*R_+r)*DV_ + o];
    }
    float kl = s_kl[o] + lbk;
    float ss = kl*kl;
    for (int off=1; off<64; off<<=1) ss += __shfl_xor(ss, off, 64);
    float kp = kl * rsqrtf(ss + 1e-12f);
    float mu = softplus_(kp);
    float ph = (float)t * p.freqs[o] - 6.2831855f * sigm(p.pope_delta[o]);
    p.k_buf[base*DKP_ + o]      = mu * cosf(ph);
    p.k_buf[base*DKP_ + 64 + o] = mu * sinf(ph);
    p.v_buf[base*DV_ + o] = s_vl[o] + lbv;
  } else {
    int o = tid - 64;
    int sel = p.qsel[h*U_+u];
    if (sel == 0){
      p.q_buf[base*DKP_ + o] = 0.f;
      p.q_buf[base*DKP_ + 64 + o] = 0.f;
    } else {
      int kq = h*E_ + sel;
      float lbq = 0.f;
      for (int r=0;r<R_;r++) lbq += s_lq[r]*p.lB_q[((size_t)kq*R_+r)*DK_+o];
      float ql = s_ql[o] + lbq;
      float ss = ql*ql;
      for (int off=1; off<64; off<<=1) ss += __shfl_xor(ss, off, 64);
      float qp = ql*rsqrtf(ss + 1e-12f);
      float mu = softplus_(qp);
      float ph = (float)t * p.freqs[o];
      p.q_buf[base*DKP_ + o]      = mu*cosf(ph);
      p.q_buf[base*DKP_ + 64 + o] = mu*sinf(ph);
    }
  }
}

// ---- KDA scan: 64 blocks x 1 wave, e-split x4, quad-DPP reduce, no barriers ----
#define LOADSET(kR,aR,qR,vR,bR,tt) {                                      \
  int tc=(tt); size_t bb = hb + tc;                                       \
  const float4* kp_=(const float4*)(p.k_buf+bb*128+d0);                   \
  const float4* ap_=(const float4*)(p.a_buf+bb*128+d0);                   \
  const float4* qp_=(const float4*)(p.q_buf+bb*128+d0);                   \
  _Pragma("unroll") for(int i_=0;i_<8;i_++){ kR[i_]=kp_[i_]; aR[i_]=ap_[i_]; qR[i_]=qp_[i_]; } \
  vR = p.v_buf[bb*64+e]; bR = p.b_buf[bb]; }

#define STEPSET(kR,aR,qR,vR,bR,tt) {                                      \
  float p0=0,p1=0,p2=0,p3=0;                                              \
  _Pragma("unroll") for(int i_=0;i_<8;i_++){                              \
    float4 sv=s4[i_]; float4 av=aR[i_]; float4 kv=kR[i_];                 \
    sv.x*=av.x; sv.y*=av.y; sv.z*=av.z; sv.w*=av.w;                       \
    p0+=kv.x*sv.x; p1+=kv.y*sv.y; p2+=kv.z*sv.z; p3+=kv.w*sv.w;           \
    s4[i_]=sv; }                                                          \
  float pt=(p0+p1)+(p2+p3);                                               \
  pt += dppq<0xB1>(pt); pt += dppq<0x4E>(pt);                             \
  float bw = bR*(vR-pt);                                                  \
  float o0=0,o1=0,o2=0,o3=0;                                              \
  _Pragma("unroll") for(int i_=0;i_<8;i_++){                              \
    float4 sv=s4[i_]; float4 kv=kR[i_]; float4 qv=qR[i_];                 \
    sv.x+=bw*kv.x; sv.y+=bw*kv.y; sv.z+=bw*kv.z; sv.w+=bw*kv.w;           \
    o0+=qv.x*sv.x; o1+=qv.y*sv.y; o2+=qv.z*sv.z; o3+=qv.w*sv.w;           \
    s4[i_]=sv; }                                                          \
  float ot=(o0+o1)+(o2+o3);                                               \
  ot += dppq<0xB1>(ot); ot += dppq<0x4E>(ot);                             \
  if (dg==0) p.attn[(size_t)(b*T_+(tt))*CC_ + h*64 + e] = ot; }

__global__ __launch_bounds__(64, 1) void k_scan(P p){
  const int h  = blockIdx.x >> 3;
  const int b  = (blockIdx.x >> 2) & 1;
  const int ec = blockIdx.x & 3;
  const int lane = threadIdx.x;
  const int dg = lane & 3;          // d-group within quad
  const int el = lane >> 2;         // 0..15
  const int e  = ec*16 + el;        // output column
  const int d0 = dg*32;
  const size_t hb = (size_t)(h*U_ + b*T_);
  float4 s4[8];
  #pragma unroll
  for (int i=0;i<8;i++) s4[i] = make_float4(0.f,0.f,0.f,0.f);
  float4 kA[8], aA[8], qA[8], kB[8], aB[8], qB[8];
  float vA, bA, vB, bB;
  LOADSET(kA,aA,qA,vA,bA, 0);
  LOADSET(kB,aB,qB,vB,bB, 1);
  for (int t=0;t<T_;t+=2){
    STEPSET(kA,aA,qA,vA,bA, t);
    LOADSET(kA,aA,qA,vA,bA, (t+2<T_)? t+2 : T_-1);
    STEPSET(kB,aB,qB,vB,bB, t+1);
    LOADSET(kB,aB,qB,vB,bB, (t+3<T_)? t+3 : T_-1);
  }
}

__global__ void k_final(P p){
  int u = blockIdx.x, b=u>>9, t=u&511;
  __shared__ float hr[16], hp[4];
  if (threadIdx.x < 16) hr[threadIdx.x] = p.Hres[(size_t)u*16+threadIdx.x];
  if (threadIdx.x < 4)  hp[threadIdx.x] = p.Hpost[(size_t)u*4+threadIdx.x];
  __syncthreads();
  for (int d = threadIdx.x; d < D_; d += 256){
    float yv = p.y[(size_t)u*D_ + d];
    float sm0 = p.stream[(((size_t)(b*N_+0)*T_)+t)*D_ + d];
    float sm1 = p.stream[(((size_t)(b*N_+1)*T_)+t)*D_ + d];
    float sm2 = p.stream[(((size_t)(b*N_+2)*T_)+t)*D_ + d];
    float sm3 = p.stream[(((size_t)(b*N_+3)*T_)+t)*D_ + d];
    #pragma unroll
    for (int n=0;n<4;n++){
      float v = hr[n*4+0]*sm0 + hr[n*4+1]*sm1 + hr[n*4+2]*sm2 + hr[n*4+3]*sm3 + hp[n]*yv;
      p.out[(((size_t)(b*N_+n)*T_)+t)*D_ + d] = v;
    }
  }
}

// ============================ host launch ============================

extern "C" void kernel_launch(void* const* d_in, const int* in_sizes, int n_in,
                              void* d_out, int out_size, void* d_ws, size_t ws_size,
                              hipStream_t stream){
  P p;
  p.stream = (const float*)d_in[0];
  p.freqs = (const float*)d_in[1];
  p.pope_delta = (const float*)d_in[2];
  p.W_q = (const float*)d_in[3]; p.W_k = (const float*)d_in[4]; p.W_v = (const float*)d_in[5];
  p.q_rw = (const float*)d_in[6]; p.kv_rw = (const float*)d_in[7];
  p.lA_q = (const float*)d_in[8];  p.lB_q = (const float*)d_in[9];
  p.lA_k = (const float*)d_in[10]; p.lB_k = (const float*)d_in[11];
  p.lA_v = (const float*)d_in[12]; p.lB_v = (const float*)d_in[13];
  p.a_up = (const float*)d_in[14]; p.a_dn = (const float*)d_in[15];
  p.b_up = (const float*)d_in[16]; p.b_dn = (const float*)d_in[17];
  p.mhc_norm = (const float*)d_in[18];
  p.phi_pre = (const float*)d_in[19]; p.phi_post = (const float*)d_in[20]; p.phi_res = (const float*)d_in[21];
  p.b_pre = (const float*)d_in[22]; p.b_post = (const float*)d_in[23]; p.b_res = (const float*)d_in[24];
  p.al_pre = (const float*)d_in[25]; p.al_post = (const float*)d_in[26]; p.al_res = (const float*)d_in[27];
  p.bn_w = (const float*)d_in[28];
  p.W_pre = (const float*)d_in[29]; p.W_o = (const float*)d_in[30];
  p.W_pg1 = (const float*)d_in[31]; p.W_pg2 = (const float*)d_in[32];
  p.out = (float*)d_out;

  char* w = (char*)d_ws;
  size_t off = 0;
  auto alloc = [&](size_t bytes)->void*{
    void* r = w + off;
    off = (off + bytes + 255) & ~(size_t)255;
    return r;
  };
  p.qsel   = (int*)alloc(H_*U_*4);
  p.kvsel  = (int*)alloc(H_*U_*4);
  p.qcnt   = (int*)alloc(HE_*4);
  p.kvcnt  = (int*)alloc(HE_*4);
  p.qlist  = (int*)alloc((size_t)HE_*U_*4);
  p.kvlist = (int*)alloc((size_t)HE_*U_*4);
  p.scale  = (float*)alloc(U_*4);
  p.mhc_partial = (float*)alloc((size_t)4*U_*1152*4);
  p.Hpre_q  = (float*)alloc((size_t)H_*U_*4*4);
  p.Hpre_kv = (float*)alloc((size_t)H_*U_*4*4);
  p.Hres    = (float*)alloc((size_t)U_*16*4);
  p.Hpost   = (float*)alloc((size_t)U_*4*4);
  p.kv_lin  = (float*)alloc((size_t)H_*U_*128*4);
  p.aup     = (float*)alloc((size_t)H_*U_*DA_*4);
  p.bup     = (float*)alloc((size_t)H_*U_*DA_*4);
  p.pre_logit  = (float*)alloc((size_t)U_*CC_*4);
  p.post_logit = (float*)alloc((size_t)U_*D_*4);
  p.la_k    = (float*)alloc((size_t)H_*U_*R_*4);
  p.la_v    = (float*)alloc((size_t)H_*U_*R_*4);
  p.la_q    = (float*)alloc((size_t)H_*U_*R_*4);
  p.q_lin   = (float*)alloc((size_t)H_*U_*64*4);
  p.a_buf   = (float*)alloc((size_t)H_*U_*DKP_*4);
  p.b_buf   = (float*)alloc((size_t)H_*U_*4);
  p.q_buf   = (float*)alloc((size_t)H_*U_*DKP_*4);
  p.k_buf   = (float*)alloc((size_t)H_*U_*DKP_*4);
  p.v_buf   = (float*)alloc((size_t)H_*U_*DV_*4);
  p.attn    = (float*)alloc((size_t)U_*CC_*4);
  p.y       = (float*)alloc((size_t)U_*D_*4);
  p.xb      = (u16*)alloc((size_t)U_*ND_*2);
  p.he_kvB = (u16*)alloc((size_t)H_*U_*D_*2);
  p.he_qB  = (u16*)alloc((size_t)H_*U_*D_*2);
  p.pgB    = (u16*)alloc((size_t)H_*U_*320*2);
  p.Bt0    = (u16*)alloc((size_t)1152*4096*2);
  p.Bt1    = (u16*)alloc((size_t)HE_*1216*1024*2);
  p.Bt2    = (u16*)alloc((size_t)HE_*128*1024*2);
  p.Bt3    = (u16*)alloc((size_t)HE_*1024*320*2);
  p.Bt4    = (u16*)alloc((size_t)1024*512*2);
  if (off > ws_size) return;

  hipMemsetAsync(p.qcnt, 0, HE_*4, stream);
  hipMemsetAsync(p.kvcnt, 0, HE_*4, stream);
  hipMemsetAsync(p.pre_logit, 0, (size_t)U_*CC_*4, stream);
  hipMemsetAsync(p.post_logit, 0, (size_t)U_*D_*4, stream);
  hipMemsetAsync(p.pgB, 0, (size_t)H_*U_*320*2, stream);
  hipMemsetAsync(p.Bt2, 0, (size_t)HE_*128*1024*2, stream);

  k_prep0<<<1152,256,0,stream>>>(p);
  k_prep1d<<<dim3(150,48),256,0,stream>>>(p);
  size_t b1s = (size_t)1216*1024;
  k_prept<<<dim3(32, 4,48),256,0,stream>>>(p.a_up,  (long)1024*DA_, DA_, DA_, p.Bt1+ 128*1024, b1s, 1024, 1024, 1024);
  k_prept<<<dim3(32, 4,48),256,0,stream>>>(p.b_up,  (long)1024*DA_, DA_, DA_, p.Bt1+ 231*1024, b1s, 1024, 1024, 1024);
  k_prept<<<dim3(32,16,48),256,0,stream>>>(p.W_pre, (long)1024*CC_, CC_, CC_, p.Bt1+ 334*1024, b1s, 1024, 1024, 1024);
  k_prept<<<dim3(32,10,48),256,0,stream>>>(p.W_pg1, (long)1024*DPG_,DPG_,DPG_,p.Bt1+ 846*1024, b1s, 1024, 1024, 1024);
  k_prept<<<dim3(32, 1,48),256,0,stream>>>(p.lA_k,  (long)1024*R_,  R_,  R_,  p.Bt1+1162*1024, b1s, 1024, 1024, 1024);
  k_prept<<<dim3(32, 1,48),256,0,stream>>>(p.lA_v,  (long)1024*R_,  R_,  R_,  p.Bt1+1178*1024, b1s, 1024, 1024, 1024);
  k_prep2d<<<dim3(64,48),256,0,stream>>>(p);
  k_prept<<<dim3(32, 1,48),256,0,stream>>>(p.lA_q,  (long)1024*R_,  R_,  R_,  p.Bt2+  64*1024, (long)128*1024, 1024, 1024, 1024);
  k_prept<<<dim3(10,32,48),256,0,stream>>>(p.W_pg2, (long)DPG_*1024,1024,1024,p.Bt3,           (long)1024*320,  320,  320,  316);
  k_prep4<<<1024,256,0,stream>>>(p);

  k_route<<<U_,256,0,stream>>>(p);
  k_mgemm<0><<<dim3(9,8,4),256,0,stream>>>(p);
  k_mhcsel<<<U_,64,0,stream>>>(p);
  k_he2<<<U_,256,0,stream>>>(p);
  k_mgemm<1><<<dim3(10,8,48),256,0,stream>>>(p);
  k_mgemm<2><<<dim3(1,8,48),256,0,stream>>>(p);
  k_stage2<<<H_*U_,128,0,stream>>>(p);
  k_mgemm<3><<<dim3(8,8,48),256,0,stream>>>(p);
  k_scan<<<64,64,0,stream>>>(p);
  k_mgemm<4><<<dim3(8,8,1),256,0,stream>>>(p);
  k_final<<<U_,256,0,stream>>>(p);
}